// Round 3
// baseline (273.155 us; speedup 1.0000x reference)
//
#include <hip/hip_runtime.h>
#include <hip/hip_bf16.h>

#define Bb 8
#define Tt 4096
#define Dd 1024
#define Hh 1024
#define Mm (Bb * Tt)
#define NCHUNK 32
#define CLEN 128

typedef float f32x4 __attribute__((ext_vector_type(4)));
typedef short bf16x8 __attribute__((ext_vector_type(8)));

__device__ __forceinline__ unsigned f2bfu(float x) {
  unsigned u = __float_as_uint(x);
  return (u + 0x7fffu + ((u >> 16) & 1u)) >> 16;  // RNE to bf16 bits
}
__device__ __forceinline__ float bflo(unsigned u) { return __uint_as_float(u << 16); }
__device__ __forceinline__ float bfhi(unsigned u) { return __uint_as_float(u & 0xffff0000u); }

// ---------------- fp32 -> bf16 conversion ----------------
__global__ void cvt_kernel(const float* __restrict__ src, unsigned short* __restrict__ dst,
                           int n4) {
  int i = blockIdx.x * blockDim.x + threadIdx.x;
  int stride = gridDim.x * blockDim.x;
  for (; i < n4; i += stride) {
    float4 v = reinterpret_cast<const float4*>(src)[i];
    ushort4 o;
    o.x = (unsigned short)f2bfu(v.x);
    o.y = (unsigned short)f2bfu(v.y);
    o.z = (unsigned short)f2bfu(v.z);
    o.w = (unsigned short)f2bfu(v.w);
    reinterpret_cast<ushort4*>(dst)[i] = o;
  }
}

__device__ __forceinline__ void async16(const unsigned short* g, unsigned short* l) {
  __builtin_amdgcn_global_load_lds(
      (const __attribute__((address_space(1))) unsigned int*)g,
      (__attribute__((address_space(3))) unsigned int*)l, 16, 0, 0);
}

// =====================================================================
// 256x256-tile 8-phase GEMM, template-faithful (no sched_barrier, 2
// vmcnt guards/iter, pointer-increment staging).
// LDS: A,B each 4 regions x 16KiB (region = 256 rows x 32 k-cols bf16).
// Pair p (phases 2p+1, 2p+2) computes region p; stages region (p+3)&3.
// A global ptr advances +32 shorts per A-stage, B likewise (sequence is
// exactly k-contiguous across prologue + all iterations; final 3 stages
// overrun into adjacent ws buffers - mapped, never consumed).
// Guards: vmcnt(4) after MFMA of ph4 & ph8 (covers next 4 phases' reads
// after the following barrier; 4-phase lead >> HBM latency).
// =====================================================================
template <int MF0>
__device__ __forceinline__ void mfma16(const bf16x8 af[4], const bf16x8 bfr[4],
                                       f32x4 (&acc)[8][4]) {
#pragma unroll
  for (int i = 0; i < 4; ++i)
#pragma unroll
    for (int j = 0; j < 4; ++j)
      acc[MF0 + i][j] =
          __builtin_amdgcn_mfma_f32_16x16x32_bf16(af[i], bfr[j], acc[MF0 + i][j], 0, 0, 0);
}

__global__ void __launch_bounds__(512, 1) gemm_kernel(
    const unsigned short* __restrict__ xb,
    const unsigned short* __restrict__ wzb,
    const unsigned short* __restrict__ whb,
    const float* __restrict__ bz,
    const float* __restrict__ bh,
    unsigned int* __restrict__ P) {
  __shared__ unsigned short lds[65536];  // A [0,32768), B [32768,65536) shorts
  const int tid = threadIdx.x;
  const int wid = tid >> 6;
  const int wm = wid >> 2;      // 0..1
  const int wn = wid & 3;       // 0..3
  const int l = tid & 63, ln = l & 15, l4 = l >> 4;

  // bijective XCD swizzle (nwg=1024, divisible by 8)
  const int id = blockIdx.x;
  const int sw = (id & 7) * 128 + (id >> 3);
  const int mb = sw >> 3, nb = sw & 7;
  const int m0 = mb * 256, h0 = nb * 128;

  // ---- staging per-thread constants (row r0 = tid>>2, swizzled k-chunk) ----
  const int r0 = tid >> 2;
  const int chunk = ((tid & 3) - (tid >> 3)) & 3;
  const unsigned short* agp = xb + (size_t)(m0 + r0) * Dd + chunk * 8;
  const int sub16 = r0 >> 4;                      // even=Wz, odd=Wh (both ops same parity)
  const int hrow0 = h0 + ((sub16 >> 1) << 4) + (r0 & 15);
  const unsigned short* bgp =
      ((sub16 & 1) ? whb : wzb) + (size_t)hrow0 * Dd + chunk * 8;
  const int dstoff = tid * 8;  // shorts within region; op2 at +4096

  auto stA = [&](int reg) {
    unsigned short* d = &lds[reg * 8192] + dstoff;
    async16(agp, d);
    async16(agp + (size_t)128 * Dd, d + 4096);
    agp += 32;
  };
  auto stB = [&](int reg) {
    unsigned short* d = &lds[32768 + reg * 8192] + dstoff;
    async16(bgp, d);
    async16(bgp + (size_t)64 * Dd, d + 4096);
    bgp += 32;
  };

  // ---- fragment read offsets (shorts within 16KiB region) ----
  int oA[8], oB[4];
#pragma unroll
  for (int mf = 0; mf < 8; ++mf) {
    const int row = wm * 128 + mf * 16 + ln;
    const int sl = (l4 + (row >> 1)) & 3;
    oA[mf] = row * 32 + sl * 8;
  }
#pragma unroll
  for (int nf = 0; nf < 4; ++nf) {
    const int row = wn * 64 + nf * 16 + ln;
    const int sl = (l4 + (row >> 1)) & 3;
    oB[nf] = row * 32 + sl * 8;
  }

  f32x4 acc[8][4];
#pragma unroll
  for (int i = 0; i < 8; ++i)
#pragma unroll
    for (int j = 0; j < 4; ++j) acc[i][j] = f32x4{0.f, 0.f, 0.f, 0.f};

  // ---- prologue: stage regions 0,1,2 (k = 0,32,64); guarantee 0,1 ----
  stA(0); stB(0);
  stA(1); stB(1);
  stA(2); stB(2);
  asm volatile("s_waitcnt vmcnt(4)" ::: "memory");
  __builtin_amdgcn_s_barrier();

#define PAIR(P, G)                                                        \
  {                                                                       \
    bf16x8 bfr[4];                                                        \
    const unsigned short* ba = &lds[(P) * 8192];                          \
    const unsigned short* bb = &lds[32768 + (P) * 8192];                  \
    bfr[0] = *(const bf16x8*)(bb + oB[0]);                                \
    bfr[1] = *(const bf16x8*)(bb + oB[1]);                                \
    bfr[2] = *(const bf16x8*)(bb + oB[2]);                                \
    bfr[3] = *(const bf16x8*)(bb + oB[3]);                                \
    {                                                                     \
      bf16x8 af[4];                                                       \
      af[0] = *(const bf16x8*)(ba + oA[0]);                               \
      af[1] = *(const bf16x8*)(ba + oA[1]);                               \
      af[2] = *(const bf16x8*)(ba + oA[2]);                               \
      af[3] = *(const bf16x8*)(ba + oA[3]);                               \
      stA(((P) + 3) & 3);                                                 \
      __builtin_amdgcn_s_barrier();                                       \
      __builtin_amdgcn_s_setprio(1);                                      \
      mfma16<0>(af, bfr, acc);                                            \
      __builtin_amdgcn_s_setprio(0);                                      \
      __builtin_amdgcn_s_barrier();                                       \
    }                                                                     \
    {                                                                     \
      bf16x8 af[4];                                                       \
      af[0] = *(const bf16x8*)(ba + oA[4]);                               \
      af[1] = *(const bf16x8*)(ba + oA[5]);                               \
      af[2] = *(const bf16x8*)(ba + oA[6]);                               \
      af[3] = *(const bf16x8*)(ba + oA[7]);                               \
      stB(((P) + 3) & 3);                                                 \
      __builtin_amdgcn_s_barrier();                                       \
      __builtin_amdgcn_s_setprio(1);                                      \
      mfma16<4>(af, bfr, acc);                                            \
      __builtin_amdgcn_s_setprio(0);                                      \
      if (G) asm volatile("s_waitcnt vmcnt(4)" ::: "memory");             \
      __builtin_amdgcn_s_barrier();                                       \
    }                                                                     \
  }

#pragma unroll 1
  for (int it = 0; it < 8; ++it) {
    PAIR(0, 0)
    PAIR(1, 1)
    PAIR(2, 0)
    PAIR(3, 1)
  }
#undef PAIR

  // drain pending LDS-DMA before block can retire (LDS gets reallocated)
  asm volatile("s_waitcnt vmcnt(0)" ::: "memory");

  // Epilogue: C/D layout col=lane&15, row=(lane>>4)*4+q.
  // nf = 2p -> k (Wz cols), nf = 2p+1 -> pre (Wh cols), same h.
#pragma unroll
  for (int p = 0; p < 2; ++p) {
    const int hcol = h0 + (wn * 2 + p) * 16 + ln;
    const float bzv = bz[hcol];
    const float bhv = bh[hcol];
#pragma unroll
    for (int mf = 0; mf < 8; ++mf) {
#pragma unroll
      for (int q = 0; q < 4; ++q) {
        const int m = m0 + wm * 128 + mf * 16 + l4 * 4 + q;
        const float kv = acc[mf][2 * p][q] + bzv;
        const float pv = acc[mf][2 * p + 1][q] + bhv;
        const float ek = __expf(kv);
        const float a = 1.f / (1.f + ek);   // 1 - sigmoid(k)
        const float z = 1.f - a;            // sigmoid(k)
        const float g = (pv >= 0.f) ? (pv + 0.5f) : (1.f / (1.f + __expf(-pv)));
        const float c = z * g;
        P[(size_t)m * Hh + hcol] = f2bfu(a) | (f2bfu(c) << 16);
      }
    }
  }
}

// ---------------- scan pass 1: per-chunk affine reduction (A, Q) ----------------
__global__ void scan_pass1(const unsigned int* __restrict__ P,
                           float* __restrict__ Pp, float* __restrict__ Qq) {
  const int h = blockIdx.x * 256 + threadIdx.x;
  const int ch = blockIdx.y;
  const int b = blockIdx.z;
  const unsigned int* p = P + ((size_t)(b * Tt + ch * CLEN)) * Hh + h;
  float A = 1.f, Q = 0.f;
#pragma unroll 8
  for (int i = 0; i < CLEN; ++i) {
    const unsigned u = p[(size_t)i * Hh];
    Q = fmaf(bflo(u), Q, bfhi(u));
    A *= bflo(u);
  }
  const int idx = ch * (Bb * Hh) + b * Hh + h;
  Pp[idx] = A;
  Qq[idx] = Q;
}

// ---------------- scan pass 2: sequential chunk combine (tiny) ----------------
__global__ void scan_pass2(const float* __restrict__ h0raw,
                           const float* __restrict__ Pp, const float* __restrict__ Qq,
                           float* __restrict__ Hinit) {
  const int bh = blockIdx.x * 256 + threadIdx.x;  // 0..8191
  const float x = h0raw[bh];
  float hs = (x >= 0.f) ? (x + 0.5f) : (1.f / (1.f + __expf(-x)));  // g(h_0)
  for (int ch = 0; ch < NCHUNK; ++ch) {
    const int idx = ch * (Bb * Hh) + bh;
    Hinit[idx] = hs;
    hs = fmaf(Pp[idx], hs, Qq[idx]);
  }
}

// ---------------- scan pass 3: in-chunk scan, write outputs ----------------
__global__ void scan_pass3(const unsigned int* __restrict__ P,
                           const float* __restrict__ Hinit,
                           float* __restrict__ out) {
  const int h = blockIdx.x * 256 + threadIdx.x;
  const int ch = blockIdx.y;
  const int b = blockIdx.z;
  float hs = Hinit[ch * (Bb * Hh) + b * Hh + h];
  const size_t base = ((size_t)(b * Tt + ch * CLEN)) * Hh + h;
  const unsigned int* p = P + base;
  float* o = out + base;
#pragma unroll 8
  for (int i = 0; i < CLEN; ++i) {
    const unsigned u = p[(size_t)i * Hh];
    hs = fmaf(bflo(u), hs, bfhi(u));
    o[(size_t)i * Hh] = hs;
  }
}

extern "C" void kernel_launch(void* const* d_in, const int* in_sizes, int n_in,
                              void* d_out, int out_size, void* d_ws, size_t ws_size,
                              hipStream_t stream) {
  const float* x  = (const float*)d_in[0];
  const float* h0 = (const float*)d_in[1];
  const float* Wz = (const float*)d_in[2];
  const float* bz = (const float*)d_in[3];
  const float* Wh = (const float*)d_in[4];
  const float* bh = (const float*)d_in[5];
  float* out = (float*)d_out;

  char* ws = (char*)d_ws;
  unsigned short* xb  = (unsigned short*)(ws);                       // 64 MiB
  unsigned short* wzb = (unsigned short*)(ws + 67108864);            // 2 MiB
  unsigned short* whb = (unsigned short*)(ws + 69206016);            // 2 MiB
  unsigned int*   P   = (unsigned int*)(ws + 71303168);              // 128 MiB
  float* Pp    = (float*)(ws + 205520896);                           // 1 MiB
  float* Qq    = (float*)(ws + 206569472);                           // 1 MiB
  float* Hinit = (float*)(ws + 207618048);                           // 1 MiB

  cvt_kernel<<<4096, 256, 0, stream>>>(x, xb, Mm * Dd / 4);
  cvt_kernel<<<1024, 256, 0, stream>>>(Wz, wzb, Hh * Dd / 4);
  cvt_kernel<<<1024, 256, 0, stream>>>(Wh, whb, Hh * Dd / 4);

  gemm_kernel<<<1024, 512, 0, stream>>>(xb, wzb, whb, bz, bh, P);

  dim3 sgrid(Hh / 256, NCHUNK, Bb);
  scan_pass1<<<sgrid, 256, 0, stream>>>(P, Pp, Qq);
  scan_pass2<<<Bb * Hh / 256, 256, 0, stream>>>(h0, Pp, Qq, Hinit);
  scan_pass3<<<sgrid, 256, 0, stream>>>(P, Hinit, out);
}